// Round 12
// baseline (177.280 us; speedup 1.0000x reference)
//
#include <hip/hip_runtime.h>
#include <hip/hip_fp16.h>
#include <math.h>

typedef unsigned short u16;
typedef _Float16 f16x8 __attribute__((ext_vector_type(8)));
typedef float f32x4 __attribute__((ext_vector_type(4)));

#define HWp 4096
#define Cc 96
#define Bb 4
#define Oo 192
#define C3 288

// ---------- fp32 workspace region (float offsets) ----------
#define OFF_WDWT  0           // [3][49][96]
#define OFF_BCAT  14112       // [192]
#define OFF_SBR   14304       // [288]
#define OFF_HBR   14592       // [288]
#define OFF_SPW   14880       // [192]
#define OFF_HPW   15072       // [192]
#define FP32_END  15264
// ---------- f16 region (u16 offsets, base = ws + FP32_END) ----------
#define BF_XTPAD  0           // [4][66][66][96]
#define BF_WOF    1672704     // 12 frag x 27 step x 64 lane x 8
#define BF_WPW    1838592     // 12 frag x 9 step x 64 lane x 8

__device__ __forceinline__ u16 f2h(float f) { return __half_as_ushort(__float2half(f)); }
__device__ __forceinline__ float h2f(u16 u) { union { __half h; u16 u; } t; t.u = u; return __half2float(t.h); }
__device__ __forceinline__ unsigned h2u(__half2 h) { union { __half2 h; unsigned u; } t; t.h = h; return t.u; }
__device__ __forceinline__ __half2 u2h(unsigned u) { union { __half2 h; unsigned u; } t; t.u = u; return t.h; }

#define PREP_N (165888 + 55296 + 14112 + 192 + 288 + 288 + 192 + 192 + 24960)
#define PREP_BLK ((PREP_N + 255) / 256)

// ---------------- prep + xtpad merged ----------------
__global__ __launch_bounds__(256) void prep_kernel(
    const float* __restrict__ x,
    const float* __restrict__ w3, const float* __restrict__ b3, const float* __restrict__ dw3,
    const float* __restrict__ g3, const float* __restrict__ be3, const float* __restrict__ m3, const float* __restrict__ v3,
    const float* __restrict__ w5, const float* __restrict__ b5, const float* __restrict__ dw5,
    const float* __restrict__ g5, const float* __restrict__ be5, const float* __restrict__ m5, const float* __restrict__ v5,
    const float* __restrict__ w7, const float* __restrict__ b7, const float* __restrict__ dw7,
    const float* __restrict__ g7, const float* __restrict__ be7, const float* __restrict__ m7, const float* __restrict__ v7,
    const float* __restrict__ wpw,
    const float* __restrict__ gp, const float* __restrict__ bp, const float* __restrict__ mp, const float* __restrict__ vp,
    float* __restrict__ ws)
{
    __shared__ u16 sT[64 * 104];
    u16* bf = (u16*)(ws + FP32_END);
    const int tid = threadIdx.x;

    if (blockIdx.x < 256) {                 // ---- xtpad interior ----
        const int b = blockIdx.x >> 6, h = blockIdx.x & 63;
        const float* xb = x + (((size_t)b * Cc) << 12) + (h << 6);
#pragma unroll
        for (int it = 0; it < 24; ++it) {
            int j = tid + it * 256;
            int c = j >> 6, p = j & 63;
            sT[p * 104 + c] = f2h(xb[((size_t)c << 12) + p]);
        }
        __syncthreads();
        u16* dst = bf + BF_XTPAD + ((size_t)(b * 66 + h + 1) * 66 + 1) * 96;
#pragma unroll
        for (int it = 0; it < 6; ++it) {
            int j = tid + it * 256;
            int pos = j / 24, c4 = j % 24;
            const u16* s = &sT[pos * 104 + c4 * 4];
            *(uint2*)(dst + pos * 96 + c4 * 4) = make_uint2(
                (unsigned)s[0] | ((unsigned)s[1] << 16),
                (unsigned)s[2] | ((unsigned)s[3] << 16));
        }
        return;
    }

    int i = (blockIdx.x - 256) * 256 + tid;
    if (i < 165888) {                       // WOF frag-linear f16
        int f = i / 13824, r = i % 13824;
        int s = r >> 9, l = r & 511;
        int lane = l >> 3, j = l & 7;
        int o = f * 16 + (lane & 15);
        int k = s * 32 + (lane >> 4) * 8 + j;
        int tap = k / 96, c = k % 96;
        float v = 0.f;
        if (o < 18)       v = w3[o * 864 + c * 9 + tap];
        else if (o < 68)  v = w5[(o - 18) * 864 + c * 9 + tap];
        else if (o < 166) v = w7[(o - 68) * 864 + c * 9 + tap];
        bf[BF_WOF + i] = f2h(v);
        return;
    }
    int j = i - 165888;
    if (j < 55296) {                        // WPW frag-linear f16
        int f = j / 4608, r = j % 4608;
        int s = r >> 9, l = r & 511;
        int lane = l >> 3, jj = l & 7;
        int o = f * 16 + (lane & 15);
        int k = s * 32 + (lane >> 4) * 8 + jj;
        bf[BF_WPW + j] = f2h(wpw[o * C3 + k]);
        return;
    }
    j -= 55296;
    if (j < 14112) {                        // wdwT [3][49][96] fp32
        int ksel = j / 4704, rem = j % 4704;
        int t = rem / 96, c = rem % 96;
        int K2 = (ksel == 0) ? 9 : (ksel == 1) ? 25 : 49;
        const float* dw = (ksel == 0) ? dw3 : (ksel == 1) ? dw5 : dw7;
        ws[OFF_WDWT + j] = (t < K2) ? dw[c * K2 + t] : 0.f;
        return;
    }
    j -= 14112;
    if (j < 192) {                          // bcat
        float v = 0.f;
        if (j < 18)       v = b3[j];
        else if (j < 68)  v = b5[j - 18];
        else if (j < 166) v = b7[j - 68];
        ws[OFF_BCAT + j] = v;
        return;
    }
    j -= 192;
    if (j < C3) {                           // sbr
        int ks = j / Cc, c = j % Cc;
        const float* g = (ks == 0) ? g3 : (ks == 1) ? g5 : g7;
        const float* v = (ks == 0) ? v3 : (ks == 1) ? v5 : v7;
        ws[OFF_SBR + j] = g[c] / sqrtf(v[c] + 1e-5f);
        return;
    }
    j -= C3;
    if (j < C3) {                           // hbr
        int ks = j / Cc, c = j % Cc;
        const float* g = (ks == 0) ? g3 : (ks == 1) ? g5 : g7;
        const float* v = (ks == 0) ? v3 : (ks == 1) ? v5 : v7;
        const float* be = (ks == 0) ? be3 : (ks == 1) ? be5 : be7;
        const float* m = (ks == 0) ? m3 : (ks == 1) ? m5 : m7;
        float inv = g[c] / sqrtf(v[c] + 1e-5f);
        ws[OFF_HBR + j] = be[c] - m[c] * inv;
        return;
    }
    j -= C3;
    if (j < Oo) { ws[OFF_SPW + j] = gp[j] / sqrtf(vp[j] + 1e-5f); return; }
    j -= Oo;
    if (j < Oo) {
        float inv = gp[j] / sqrtf(vp[j] + 1e-5f);
        ws[OFF_HPW + j] = bp[j] - mp[j] * inv;
        return;
    }
    j -= Oo;
    if (j < 24960) {                        // halo zero
        int c4 = j % 24, rem = j / 24;
        int cell = rem % 260, bb = rem / 260;
        int row, col;
        if (cell < 66)       { row = 0;  col = cell; }
        else if (cell < 132) { row = 65; col = cell - 66; }
        else if (cell < 196) { row = cell - 132 + 1; col = 0; }
        else                 { row = cell - 196 + 1; col = 65; }
        u16* dst = bf + BF_XTPAD + ((size_t)(bb * 66 + row) * 66 + col) * 96 + c4 * 4;
        *(uint2*)dst = make_uint2(0u, 0u);
        return;
    }
}

// one gather tap: compile-time SEG/T/GT, accumulates into acc<SEG>
#define GATHER_TAP(SEG, T, GT) do {                                          \
    const uint4 e = sWI[((GT) << 4) + q];                                    \
    const __half2 wAh = u2h(e.x), wBh = u2h(e.y);                            \
    const __half2 w00b = __low2half2(wAh), w01b = __high2half2(wAh);         \
    const __half2 w10b = __low2half2(wBh), w11b = __high2half2(wBh);         \
    const unsigned d01 = e.w & 0xffffu, d10 = e.w >> 16;                     \
    const uint4 u00 = *(const uint4*)(xcb + e.z);                            \
    const uint4 u01 = *(const uint4*)(xcb + e.z + d01);                      \
    const uint4 u10 = *(const uint4*)(xcb + e.z + d10);                      \
    const uint4 u11 = *(const uint4*)(xcb + e.z + d10 + d01);                \
    const float4 wda = *(const float4*)(wdT##SEG + (T) * 96);                \
    const float4 wdb = *(const float4*)(wdT##SEG + (T) * 96 + 4);            \
    const unsigned a00[4] = {u00.x, u00.y, u00.z, u00.w};                    \
    const unsigned a01[4] = {u01.x, u01.y, u01.z, u01.w};                    \
    const unsigned a10[4] = {u10.x, u10.y, u10.z, u10.w};                    \
    const unsigned a11[4] = {u11.x, u11.y, u11.z, u11.w};                    \
    const float wd[8] = {wda.x, wda.y, wda.z, wda.w, wdb.x, wdb.y, wdb.z, wdb.w}; \
    _Pragma("unroll")                                                        \
    for (int d = 0; d < 4; ++d) {                                            \
        __half2 v = __hmul2(w00b, u2h(a00[d]));                              \
        v = __hfma2(w01b, u2h(a01[d]), v);                                   \
        v = __hfma2(w10b, u2h(a10[d]), v);                                   \
        v = __hfma2(w11b, u2h(a11[d]), v);                                   \
        acc##SEG[2 * d]     = fmaf(wd[2 * d],     __low2float(v),  acc##SEG[2 * d]);     \
        acc##SEG[2 * d + 1] = fmaf(wd[2 * d + 1], __high2float(v), acc##SEG[2 * d + 1]); \
    }                                                                        \
} while (0)

// per-segment BN + ReLU + f16 pack epilogue
#define SEG_EPI(SEG) do {                                                    \
    const int cb = (SEG) * Cc + c;                                           \
    const float4 sa = *(const float4*)(ws + OFF_SBR + cb);                   \
    const float4 sb = *(const float4*)(ws + OFF_SBR + cb + 4);               \
    const float4 ha = *(const float4*)(ws + OFF_HBR + cb);                   \
    const float4 hb = *(const float4*)(ws + OFF_HBR + cb + 4);               \
    const float ss[8] = {sa.x, sa.y, sa.z, sa.w, sb.x, sb.y, sb.z, sb.w};    \
    const float hh8[8] = {ha.x, ha.y, ha.z, ha.w, hb.x, hb.y, hb.z, hb.w};   \
    unsigned rr[4];                                                          \
    _Pragma("unroll")                                                        \
    for (int d = 0; d < 4; ++d) {                                            \
        float lo = fmaxf(fmaf(acc##SEG[2 * d],     ss[2 * d],     hh8[2 * d]),     0.f); \
        float hi = fmaxf(fmaf(acc##SEG[2 * d + 1], ss[2 * d + 1], hh8[2 * d + 1]), 0.f); \
        rr[d] = h2u(__floats2half2_rn(lo, hi));                              \
    }                                                                        \
    *(uint4*)(ytile + q * 296 + cb) = make_uint4(rr[0], rr[1], rr[2], rr[3]); \
} while (0)

// ---------------- mega kernel: offconv -> sampling -> depthwise -> pwconv, fully fused ----------------
__global__ __launch_bounds__(256, 4) void mega_kernel(
    const float* __restrict__ ws, float* __restrict__ out)
{
    __shared__ uint4 regA[1328];           // 21248 B: sX patch, then sWI table
    __shared__ u16  regB[4736];            //  9472 B: soff (f16), then ytile
    u16* sX = (u16*)regA;
    uint4* sWI = regA;
    u16* soff = regB;
    u16* ytile = regB;

    const u16* bf = (const u16*)(ws + FP32_END);
    const u16* xp = bf + BF_XTPAD;
    const int tid = threadIdx.x;
    const int lane = tid & 63, wid = tid >> 6;
    const int lane15 = lane & 15, quad = lane >> 4;

    // XCD-aware swizzle: 1024 blocks -> (batch, tile)
    const int bx = blockIdx.x;
    const int xcd = bx & 7;
    const int b = xcd >> 1;
    const int tile = ((bx >> 3) << 1) + (xcd & 1);
    const int p0 = tile * 16;
    const int h = p0 >> 6;
    const int w0 = p0 & 63;

    // ---- phase 1: load 3-row x 18-col patch into sX ----
    {
        const u16* src = xp + ((size_t)(b * 66 + h) * 66 + w0) * 96;
        for (int j = tid; j < 1296; j += 256) {
            int r = j / 432;
            int rem = j % 432;
            int col = rem / 24, c4 = rem % 24;
            uint2 v = *(const uint2*)(src + ((size_t)(r * 66 + col)) * 96 + c4 * 4);
            *(uint2*)(&sX[(r * 18 + col) * 104 + c4 * 4]) = v;
        }
    }
    __syncthreads();

    // ---- phase 2: offset conv MFMA (M=192 as 12 frags / 4 waves, N=16, K=864) ----
    {
        const u16* wof = bf + BF_WOF;
        f32x4 acc[3];
#pragma unroll
        for (int ff = 0; ff < 3; ++ff) acc[ff] = (f32x4){0.f, 0.f, 0.f, 0.f};
#pragma unroll
        for (int tap = 0; tap < 9; ++tap) {
            const int ky2 = tap / 3, kx2 = tap % 3;
            const u16* brow = &sX[(ky2 * 18 + kx2 + lane15) * 104 + quad * 8];
#pragma unroll
            for (int cc = 0; cc < 3; ++cc) {
                f16x8 bb = *(const f16x8*)(brow + cc * 32);
                const int s = tap * 3 + cc;
#pragma unroll
                for (int ff = 0; ff < 3; ++ff) {
                    const int f = wid * 3 + ff;
                    f16x8 a = *(const f16x8*)(wof + ((size_t)(f * 27 + s) * 64 + lane) * 8);
                    acc[ff] = __builtin_amdgcn_mfma_f32_16x16x32_f16(a, bb, acc[ff], 0, 0, 0);
                }
            }
        }
        const float* bcat = ws + OFF_BCAT;
#pragma unroll
        for (int ff = 0; ff < 3; ++ff) {
#pragma unroll
            for (int r = 0; r < 4; ++r) {
                int co = (wid * 3 + ff) * 16 + quad * 4 + r;
                soff[co * 16 + lane15] = f2h(acc[ff][r] + bcat[co]);
            }
        }
    }
    __syncthreads();   // sX reads done; soff complete

    // ---- phase 3: bilinear weight/index table (83 taps x 16 pos) -> sWI (clobbers sX) ----
    for (int i = tid; i < 1328; i += 256) {
        int gt = i >> 4, q = i & 15;
        int K, K2, R, tb, t;
        if (gt < 9)       { K = 3; K2 = 9;  R = 1; tb = 0;  t = gt; }
        else if (gt < 34) { K = 5; K2 = 25; R = 2; tb = 18; t = gt - 9; }
        else              { K = 7; K2 = 49; R = 3; tb = 68; t = gt - 34; }
        int ky = t / K - R, kx = t % K - R;
        float dy = h2f(soff[(tb + t) * 16 + q]);
        float dx = h2f(soff[(tb + K2 + t) * 16 + q]);
        float py = fminf(fmaxf((float)(h + ky) + dy, 0.f), 63.f);
        float px = fminf(fmaxf((float)(w0 + q + kx) + dx, 0.f), 63.f);
        float fy = floorf(py), fx = floorf(px);
        int y0 = (int)fy, x0 = (int)fx;
        float wy = py - fy, wx = px - fx;
        int y1 = min(y0 + 1, 63), x1 = min(x0 + 1, 63);
        float w11 = wy * wx;
        float w10 = wy - w11;
        float w01 = wx - w11;
        float w00 = 1.f - wy - wx + w11;
        unsigned wA = h2u(__floats2half2_rn(w00, w01));
        unsigned wB = h2u(__floats2half2_rn(w10, w11));
        unsigned o00 = (unsigned)((y0 + 1) * 66 + (x0 + 1)) * 192u;
        unsigned d01 = (unsigned)(x1 - x0) * 192u;
        unsigned d10 = (unsigned)(y1 - y0) * 12672u;
        sWI[i] = make_uint4(wA, wB, o00, d01 | (d10 << 16));
    }
    __syncthreads();   // soff consumed; sWI ready

    // ---- phase 4: merged ky-major gather sweep (all 3 branches) + BN + ReLU -> ytile ----
    if (tid < 192) {
        const int c8 = tid % 12;
        const int q  = tid / 12;
        const int c = c8 * 8;
        const u16* xh = xp + (size_t)b * 66 * 66 * 96;
        const char* xcb = (const char*)xh + c * 2;
        const float* wdT0 = ws + OFF_WDWT + 0 * 4704 + c;
        const float* wdT1 = ws + OFF_WDWT + 1 * 4704 + c;
        const float* wdT2 = ws + OFF_WDWT + 2 * 4704 + c;

        float acc0[8], acc1[8], acc2[8];
#pragma unroll
        for (int k = 0; k < 8; ++k) { acc0[k] = 0.f; acc1[k] = 0.f; acc2[k] = 0.f; }

        // ky-major interleave: taps of all branches sharing the same source-row
        // strip are processed back-to-back (L1 reuse across branches).
#pragma unroll
        for (int ky = -3; ky <= 3; ++ky) {
            if (ky >= -1 && ky <= 1) {
#pragma unroll
                for (int kx = -1; kx <= 1; ++kx) {
                    const int t = (ky + 1) * 3 + (kx + 1);
                    GATHER_TAP(0, t, t);
                }
            }
            if (ky >= -2 && ky <= 2) {
#pragma unroll
                for (int kx = -2; kx <= 2; ++kx) {
                    const int t = (ky + 2) * 5 + (kx + 2);
                    GATHER_TAP(1, t, 9 + t);
                }
            }
#pragma unroll
            for (int kx = -3; kx <= 3; ++kx) {
                const int t = (ky + 3) * 7 + (kx + 3);
                GATHER_TAP(2, t, 34 + t);
            }
        }

        SEG_EPI(0);
        SEG_EPI(1);
        SEG_EPI(2);
    }
    __syncthreads();   // sWI consumed; ytile ready

    // ---- phase 5: pointwise MFMA (M=192 as 12 frags / 4 waves, N=16, K=288) + BN + ReLU ----
    {
        const u16* wpw = bf + BF_WPW;
        f32x4 acc[3];
#pragma unroll
        for (int ff = 0; ff < 3; ++ff) acc[ff] = (f32x4){0.f, 0.f, 0.f, 0.f};
        const u16* brow = &ytile[lane15 * 296 + quad * 8];
#pragma unroll
        for (int s = 0; s < 9; ++s) {
            f16x8 bb = *(const f16x8*)(brow + s * 32);
#pragma unroll
            for (int ff = 0; ff < 3; ++ff) {
                const int f = wid * 3 + ff;
                f16x8 a = *(const f16x8*)(wpw + ((size_t)(f * 9 + s) * 64 + lane) * 8);
                acc[ff] = __builtin_amdgcn_mfma_f32_16x16x32_f16(a, bb, acc[ff], 0, 0, 0);
            }
        }
        const float* spw = ws + OFF_SPW;
        const float* hpw = ws + OFF_HPW;
        const int p = p0 + lane15;
#pragma unroll
        for (int ff = 0; ff < 3; ++ff) {
#pragma unroll
            for (int r = 0; r < 4; ++r) {
                int o = (wid * 3 + ff) * 16 + quad * 4 + r;
                out[(((size_t)(b * Oo + o)) << 12) + p] =
                    fmaxf(fmaf(acc[ff][r], spw[o], hpw[o]), 0.f);
            }
        }
    }
}

extern "C" void kernel_launch(void* const* d_in, const int* in_sizes, int n_in,
                              void* d_out, int out_size, void* d_ws, size_t ws_size,
                              hipStream_t stream)
{
    const float* x     = (const float*)d_in[0];
    const float* w3    = (const float*)d_in[1];
    const float* b3    = (const float*)d_in[2];
    const float* dw3   = (const float*)d_in[3];
    const float* g3    = (const float*)d_in[4];
    const float* be3   = (const float*)d_in[5];
    const float* m3    = (const float*)d_in[6];
    const float* v3    = (const float*)d_in[7];
    const float* w5    = (const float*)d_in[8];
    const float* b5    = (const float*)d_in[9];
    const float* dw5   = (const float*)d_in[10];
    const float* g5    = (const float*)d_in[11];
    const float* be5   = (const float*)d_in[12];
    const float* m5    = (const float*)d_in[13];
    const float* v5    = (const float*)d_in[14];
    const float* w7    = (const float*)d_in[15];
    const float* b7    = (const float*)d_in[16];
    const float* dw7   = (const float*)d_in[17];
    const float* g7    = (const float*)d_in[18];
    const float* be7   = (const float*)d_in[19];
    const float* m7    = (const float*)d_in[20];
    const float* v7    = (const float*)d_in[21];
    const float* wpw   = (const float*)d_in[22];
    const float* gp    = (const float*)d_in[23];
    const float* bp    = (const float*)d_in[24];
    const float* mp    = (const float*)d_in[25];
    const float* vp    = (const float*)d_in[26];

    float* ws = (float*)d_ws;
    float* out = (float*)d_out;

    {   // 1) prep + xtpad (merged)
        prep_kernel<<<256 + PREP_BLK, 256, 0, stream>>>(
            x,
            w3, b3, dw3, g3, be3, m3, v3,
            w5, b5, dw5, g5, be5, m5, v5,
            w7, b7, dw7, g7, be7, m7, v7,
            wpw, gp, bp, mp, vp, ws);
    }
    {   // 2) fully fused pipeline, XCD-swizzled 1-D grid
        mega_kernel<<<1024, 256, 0, stream>>>(ws, out);
    }
}